// Round 7
// baseline (160.619 us; speedup 1.0000x reference)
//
#include <hip/hip_runtime.h>
#include <hip/hip_bf16.h>

// Problem constants (fixed by the reference): B=16, V=8192, N=2048, H=128, C_OUT=7
#define B_GR   16
#define V_PTS  8192
#define N_RES  2048
#define H_DIM  128
#define C_OUT  7
#define SEGS   16                    // pool kernel: residue segments per graph

// argmin decomposition
// R6 lesson: __launch_bounds__(256,8) + VPT=4 forced VGPR<=32 -> compiler
// remat bloat (~15.5 ops/pair vs 10 static). Fix: shrink per-thread state
// (VPT=2) so the clean 10-op/pair stream fits 32 VGPR at 8 waves/SIMD.
#define NSPLIT 8                     // residue splits per graph
#define NL     (N_RES / NSPLIT)      // 256 residues per block
#define VPT    2                     // vertices per thread (2 independent chains)
#define VBLK   (256 * VPT)           // 512 vertices per block
#define VBLKS  (V_PTS / VBLK)        // 16 vertex-blocks per graph
// grid = B * VBLKS * NSPLIT = 16*16*8 = 2048 blocks -> 8 blocks/CU, 32 waves/CU

// ---------------------------------------------------------------------------
// Kernel 1: partial nearest-residue argmin over a 256-residue slice, 2
// vertices per thread. Bit-exact replication of the reference fp32 sequence:
//   d = fadd( fma(-2, dot, vsq), csq ),  dot = fadd(fadd(x*cx, y*cy), z*cz)
// (fma(-2,dot,vsq) == RN(vsq - 2*dot) exactly since scaling by 2 is exact.)
// Partials merged across splits with atomicMin on packed
// (monotone-flipped dist bits << 32) | global_idx — equal dists pick the
// smaller index, matching np.argmin first-occurrence. d == -0.0 impossible
// (csq >= +0), so the flip transform is a strict order-embedding.
// ---------------------------------------------------------------------------
__global__ __launch_bounds__(256, 8) void k_argmin(const float* __restrict__ verts,
                                                   const float* __restrict__ coords,
                                                   unsigned long long* __restrict__ mi64) {
    __shared__ float4 sc[NL];                          // 4 KB
    const int b  = blockIdx.x / (VBLKS * NSPLIT);
    const int r  = blockIdx.x % (VBLKS * NSPLIT);
    const int vb = r / NSPLIT;
    const int ns = r % NSPLIT;

    const float* cbase = coords + ((size_t)b * N_RES + ns * NL) * 3;
    for (int i = threadIdx.x; i < NL; i += 256) {
        float x = cbase[i * 3 + 0];
        float y = cbase[i * 3 + 1];
        float z = cbase[i * 3 + 2];
        float csq = __fadd_rn(__fadd_rn(__fmul_rn(x, x), __fmul_rn(y, y)), __fmul_rn(z, z));
        sc[i] = make_float4(x, y, z, csq);
    }
    __syncthreads();

    const int vbase = vb * VBLK + threadIdx.x;         // vertex index within graph
    const float* vp = verts + (size_t)b * V_PTS * 3;

    float vx[VPT], vy[VPT], vz[VPT], vsq[VPT], best[VPT];
    int bi[VPT];
#pragma unroll
    for (int k = 0; k < VPT; ++k) {
        const int v = vbase + k * 256;
        vx[k] = vp[v * 3 + 0];
        vy[k] = vp[v * 3 + 1];
        vz[k] = vp[v * 3 + 2];
        vsq[k] = __fadd_rn(__fadd_rn(__fmul_rn(vx[k], vx[k]), __fmul_rn(vy[k], vy[k])),
                           __fmul_rn(vz[k], vz[k]));
        best[k] = 3.402823466e+38f;
        bi[k] = 0;
    }

    // unroll 2: n stays a uniform (SGPR) operand for the index cndmask;
    // c-register footprint stays at 8 VGPRs.
#pragma unroll 2
    for (int n = 0; n < NL; ++n) {
        const float4 c = sc[n];
#pragma unroll
        for (int k = 0; k < VPT; ++k) {
            float dot = __fadd_rn(__fadd_rn(__fmul_rn(vx[k], c.x), __fmul_rn(vy[k], c.y)),
                                  __fmul_rn(vz[k], c.z));
            float d = __fadd_rn(fmaf(-2.0f, dot, vsq[k]), c.w);
            bool m = d < best[k];                      // strict <: first index wins
            best[k] = m ? d : best[k];
            bi[k]   = m ? n : bi[k];
        }
    }

#pragma unroll
    for (int k = 0; k < VPT; ++k) {
        unsigned int bits = __float_as_uint(best[k]);
        unsigned int key  = bits ^ (unsigned int)(((int)bits >> 31) | 0x80000000);
        unsigned long long packed =
            ((unsigned long long)key << 32) | (unsigned int)(ns * NL + bi[k]);
        atomicMin(&mi64[(size_t)b * V_PTS + vbase + k * 256], packed);
    }
}

// ---------------------------------------------------------------------------
// Kernel 2: rebuild per-graph hit mask in LDS from packed argmin (low 32 bits
// = index), masked-sum a 128-residue slice of feats with float4 loads.
// Grid: B*SEGS = 256 blocks, 256 threads.
// ---------------------------------------------------------------------------
__global__ __launch_bounds__(256) void k_pool(const unsigned long long* __restrict__ mi64,
                                              const float* __restrict__ feats,
                                              float* __restrict__ partial) {
    __shared__ float msk[N_RES];                        // 8 KB
    __shared__ float4 red[8][32];
    const int b   = blockIdx.x >> 4;
    const int seg = blockIdx.x & (SEGS - 1);

    for (int i = threadIdx.x; i < N_RES; i += 256) msk[i] = 0.0f;
    __syncthreads();

    const unsigned long long* mb = mi64 + (size_t)b * V_PTS;
    for (int v = threadIdx.x; v < V_PTS; v += 256)
        msk[(unsigned int)mb[v]] = 1.0f;                // race benign: all write 1
    __syncthreads();

    const int q = threadIdx.x & 31;                     // float4 column (h = 4q..4q+3)
    const int s = threadIdx.x >> 5;                     // n-slice 0..7
    const int n0 = seg * (N_RES / SEGS);
    const float4* fb4 = (const float4*)(feats + ((size_t)b * N_RES + n0) * H_DIM);

    float4 acc = make_float4(0.f, 0.f, 0.f, 0.f);
#pragma unroll
    for (int n = 0; n < N_RES / SEGS / 8; ++n) {
        const int nn = s + n * 8;
        const float m = msk[n0 + nn];
        const float4 f = fb4[(size_t)nn * 32 + q];
        acc.x = fmaf(f.x, m, acc.x);
        acc.y = fmaf(f.y, m, acc.y);
        acc.z = fmaf(f.z, m, acc.z);
        acc.w = fmaf(f.w, m, acc.w);
    }
    red[s][q] = acc;
    __syncthreads();

    if (s == 0) {
        float4 t = acc;
#pragma unroll
        for (int i = 1; i < 8; ++i) {
            t.x += red[i][q].x; t.y += red[i][q].y;
            t.z += red[i][q].z; t.w += red[i][q].w;
        }
        ((float4*)partial)[((size_t)b * SEGS + seg) * 32 + q] = t;
    }
}

// ---------------------------------------------------------------------------
// Kernel 3: per-graph block — reduce 16 seg partials -> pooled[H], then
// relu(pooled@W1+b1)@W2+b2 -> out[b][7]. 16 blocks x 128 threads.
// ---------------------------------------------------------------------------
__global__ __launch_bounds__(128) void k_mlp(const float* __restrict__ partial,
                                             const float* __restrict__ W1,
                                             const float* __restrict__ b1,
                                             const float* __restrict__ W2,
                                             const float* __restrict__ b2,
                                             float* __restrict__ out) {
    __shared__ float pooled[H_DIM];
    __shared__ float h1[H_DIM];
    const int b = blockIdx.x;
    const int j = threadIdx.x;

    float s = 0.0f;
#pragma unroll
    for (int g = 0; g < SEGS; ++g)
        s += partial[((size_t)b * SEGS + g) * H_DIM + j];
    pooled[j] = s;
    __syncthreads();

    float acc = b1[j];
#pragma unroll 8
    for (int hh = 0; hh < H_DIM; ++hh)
        acc = fmaf(pooled[hh], W1[hh * H_DIM + j], acc);
    h1[j] = fmaxf(acc, 0.0f);
    __syncthreads();

    if (j < C_OUT) {
        float o = b2[j];
#pragma unroll 8
        for (int hh = 0; hh < H_DIM; ++hh)
            o = fmaf(h1[hh], W2[hh * C_OUT + j], o);
        out[(size_t)b * C_OUT + j] = o;
    }
}

extern "C" void kernel_launch(void* const* d_in, const int* in_sizes, int n_in,
                              void* d_out, int out_size, void* d_ws, size_t ws_size,
                              hipStream_t stream) {
    const float* verts  = (const float*)d_in[0];   // [B,V,3]
    const float* coords = (const float*)d_in[1];   // [B,N,3]
    const float* feats  = (const float*)d_in[2];   // [B,N,H]
    const float* W1     = (const float*)d_in[3];   // [H,H]
    const float* b1     = (const float*)d_in[4];   // [H]
    const float* W2     = (const float*)d_in[5];   // [H,C_OUT]
    const float* b2     = (const float*)d_in[6];   // [C_OUT]
    float* out = (float*)d_out;                    // [B,C_OUT]

    // workspace layout
    unsigned long long* mi64 = (unsigned long long*)d_ws;                 // B*V u64 = 1 MB
    float* partial = (float*)((char*)d_ws + (size_t)B_GR * V_PTS * 8);    // B*SEGS*H = 128 KB

    hipMemsetAsync(mi64, 0xFF, (size_t)B_GR * V_PTS * 8, stream);         // graph-legal memset node
    k_argmin<<<B_GR * VBLKS * NSPLIT, 256, 0, stream>>>(verts, coords, mi64);
    k_pool  <<<B_GR * SEGS,           256, 0, stream>>>(mi64, feats, partial);
    k_mlp   <<<B_GR,                  128, 0, stream>>>(partial, W1, b1, W2, b2, out);
}

// Round 8
// 151.254 us; speedup vs baseline: 1.0619x; 1.0619x over previous
//
#include <hip/hip_runtime.h>
#include <hip/hip_bf16.h>

// Problem constants (fixed by the reference): B=16, V=8192, N=2048, H=128, C_OUT=7
#define B_GR   16
#define V_PTS  8192
#define N_RES  2048
#define H_DIM  128
#define C_OUT  7
#define SEGS   16                    // pool kernel: residue segments per graph

// argmin decomposition (R3-best structure + packed-fp32 math)
// R6/R7 lesson: constant ~11-instr per-n overhead -> maximize VPT; extra
// waves don't help. R8: cut instr/pair with v_pk_*_f32 (VOP3P packed fp32,
// bit-identical RN per component). Vertices paired into float2 lanes.
#define NSPLIT 16                    // residue splits per graph
#define NL     (N_RES / NSPLIT)      // 128 residues per block
#define VPT    8                     // vertices per thread = 4 packed pairs
#define NP     4                     // packed pairs per thread
#define VBLK   (256 * VPT)           // 2048 vertices per block
#define VBLKS  (V_PTS / VBLK)        // 4 vertex-blocks per graph
// grid = B * VBLKS * NSPLIT = 1024 blocks -> 4 blocks/CU, 16 waves/CU

typedef float v2f __attribute__((ext_vector_type(2)));

// ---------------------------------------------------------------------------
// Kernel 1: partial nearest-residue argmin over a 128-residue slice.
// Bit-exact replication of the reference fp32 sequence PER COMPONENT:
//   d = fadd( fma(-2, dot, vsq), csq ),  dot = fadd(fadd(x*cx, y*cy), z*cz)
// packed 2-wide via v_pk_{mul,add,fma}_f32 (IEEE RN per half, identical to
// scalar). fp contract OFF so mul/add never fuse beyond the one explicit fma
// (fma(-2,dot,vsq) == RN(vsq-2*dot) exactly since scaling by 2 is exact).
// Partials merged with atomicMin on packed (flipped dist bits<<32)|idx:
// ties pick the smaller index = np.argmin first-occurrence; d==-0.0
// impossible (csq >= +0) so the flip is a strict order-embedding.
// ---------------------------------------------------------------------------
__global__ __launch_bounds__(256, 4) void k_argmin(const float* __restrict__ verts,
                                                   const float* __restrict__ coords,
                                                   unsigned long long* __restrict__ mi64) {
#pragma clang fp contract(off)
    __shared__ float4 sc[NL];                          // 2 KB
    const int b  = blockIdx.x / (VBLKS * NSPLIT);
    const int r  = blockIdx.x % (VBLKS * NSPLIT);
    const int vb = r / NSPLIT;
    const int ns = r % NSPLIT;

    const float* cbase = coords + ((size_t)b * N_RES + ns * NL) * 3;
    if (threadIdx.x < NL) {
        const int i = threadIdx.x;
        float x = cbase[i * 3 + 0];
        float y = cbase[i * 3 + 1];
        float z = cbase[i * 3 + 2];
        float csq = __fadd_rn(__fadd_rn(__fmul_rn(x, x), __fmul_rn(y, y)), __fmul_rn(z, z));
        sc[i] = make_float4(x, y, z, csq);
    }
    __syncthreads();

    const int vbase = vb * VBLK + threadIdx.x;         // vertex index within graph
    const float* vp = verts + (size_t)b * V_PTS * 3;

    // packed pair p holds vertices (vbase + p*256) [lo] and (vbase + (p+4)*256) [hi]
    v2f vx2[NP], vy2[NP], vz2[NP], vsq2[NP], best2[NP];
    int bi[VPT];
#pragma unroll
    for (int p = 0; p < NP; ++p) {
        const int va = vbase + p * 256;
        const int vb2 = vbase + (p + 4) * 256;
        float ax = vp[va * 3 + 0], ay = vp[va * 3 + 1], az = vp[va * 3 + 2];
        float bx = vp[vb2 * 3 + 0], by = vp[vb2 * 3 + 1], bz = vp[vb2 * 3 + 2];
        vx2[p] = (v2f){ax, bx};
        vy2[p] = (v2f){ay, by};
        vz2[p] = (v2f){az, bz};
        float sa = __fadd_rn(__fadd_rn(__fmul_rn(ax, ax), __fmul_rn(ay, ay)), __fmul_rn(az, az));
        float sb = __fadd_rn(__fadd_rn(__fmul_rn(bx, bx), __fmul_rn(by, by)), __fmul_rn(bz, bz));
        vsq2[p] = (v2f){sa, sb};
        best2[p] = (v2f){3.402823466e+38f, 3.402823466e+38f};
        bi[2 * p] = 0;
        bi[2 * p + 1] = 0;
    }

    const v2f neg2 = (v2f){-2.0f, -2.0f};
#pragma unroll 2
    for (int n = 0; n < NL; ++n) {
        const float4 c = sc[n];
        const v2f cX = (v2f){c.x, c.x};
        const v2f cY = (v2f){c.y, c.y};
        const v2f cZ = (v2f){c.z, c.z};
        const v2f cW = (v2f){c.w, c.w};
#pragma unroll
        for (int p = 0; p < NP; ++p) {
            v2f m1 = vx2[p] * cX;                      // v_pk_mul_f32
            v2f m2 = vy2[p] * cY;
            v2f a1 = m1 + m2;                          // v_pk_add_f32
            v2f m3 = vz2[p] * cZ;
            v2f dt = a1 + m3;
            v2f t  = __builtin_elementwise_fma(neg2, dt, vsq2[p]);  // v_pk_fma_f32
            v2f d  = t + cW;
            bool mlo = d.x < best2[p].x;               // strict <: first index wins
            bool mhi = d.y < best2[p].y;
            best2[p].x = mlo ? d.x : best2[p].x;
            bi[2 * p]  = mlo ? n : bi[2 * p];
            best2[p].y = mhi ? d.y : best2[p].y;
            bi[2 * p + 1] = mhi ? n : bi[2 * p + 1];
        }
    }

#pragma unroll
    for (int p = 0; p < NP; ++p) {
#pragma unroll
        for (int h = 0; h < 2; ++h) {
            const int v = vbase + (p + 4 * h) * 256;
            const float bv = h ? best2[p].y : best2[p].x;
            unsigned int bits = __float_as_uint(bv);
            unsigned int key  = bits ^ (unsigned int)(((int)bits >> 31) | 0x80000000);
            unsigned long long packed =
                ((unsigned long long)key << 32) | (unsigned int)(ns * NL + bi[2 * p + h]);
            atomicMin(&mi64[(size_t)b * V_PTS + v], packed);
        }
    }
}

// ---------------------------------------------------------------------------
// Kernel 2: rebuild per-graph hit mask in LDS from packed argmin (low 32 bits
// = index), masked-sum a 128-residue slice of feats with float4 loads.
// Grid: B*SEGS = 256 blocks, 256 threads.
// ---------------------------------------------------------------------------
__global__ __launch_bounds__(256) void k_pool(const unsigned long long* __restrict__ mi64,
                                              const float* __restrict__ feats,
                                              float* __restrict__ partial) {
    __shared__ float msk[N_RES];                        // 8 KB
    __shared__ float4 red[8][32];
    const int b   = blockIdx.x >> 4;
    const int seg = blockIdx.x & (SEGS - 1);

    for (int i = threadIdx.x; i < N_RES; i += 256) msk[i] = 0.0f;
    __syncthreads();

    const unsigned long long* mb = mi64 + (size_t)b * V_PTS;
    for (int v = threadIdx.x; v < V_PTS; v += 256)
        msk[(unsigned int)mb[v]] = 1.0f;                // race benign: all write 1
    __syncthreads();

    const int q = threadIdx.x & 31;                     // float4 column (h = 4q..4q+3)
    const int s = threadIdx.x >> 5;                     // n-slice 0..7
    const int n0 = seg * (N_RES / SEGS);
    const float4* fb4 = (const float4*)(feats + ((size_t)b * N_RES + n0) * H_DIM);

    float4 acc = make_float4(0.f, 0.f, 0.f, 0.f);
#pragma unroll
    for (int n = 0; n < N_RES / SEGS / 8; ++n) {
        const int nn = s + n * 8;
        const float m = msk[n0 + nn];
        const float4 f = fb4[(size_t)nn * 32 + q];
        acc.x = fmaf(f.x, m, acc.x);
        acc.y = fmaf(f.y, m, acc.y);
        acc.z = fmaf(f.z, m, acc.z);
        acc.w = fmaf(f.w, m, acc.w);
    }
    red[s][q] = acc;
    __syncthreads();

    if (s == 0) {
        float4 t = acc;
#pragma unroll
        for (int i = 1; i < 8; ++i) {
            t.x += red[i][q].x; t.y += red[i][q].y;
            t.z += red[i][q].z; t.w += red[i][q].w;
        }
        ((float4*)partial)[((size_t)b * SEGS + seg) * 32 + q] = t;
    }
}

// ---------------------------------------------------------------------------
// Kernel 3: per-graph block — reduce 16 seg partials -> pooled[H], then
// relu(pooled@W1+b1)@W2+b2 -> out[b][7]. 16 blocks x 128 threads.
// ---------------------------------------------------------------------------
__global__ __launch_bounds__(128) void k_mlp(const float* __restrict__ partial,
                                             const float* __restrict__ W1,
                                             const float* __restrict__ b1,
                                             const float* __restrict__ W2,
                                             const float* __restrict__ b2,
                                             float* __restrict__ out) {
    __shared__ float pooled[H_DIM];
    __shared__ float h1[H_DIM];
    const int b = blockIdx.x;
    const int j = threadIdx.x;

    float s = 0.0f;
#pragma unroll
    for (int g = 0; g < SEGS; ++g)
        s += partial[((size_t)b * SEGS + g) * H_DIM + j];
    pooled[j] = s;
    __syncthreads();

    float acc = b1[j];
#pragma unroll 8
    for (int hh = 0; hh < H_DIM; ++hh)
        acc = fmaf(pooled[hh], W1[hh * H_DIM + j], acc);
    h1[j] = fmaxf(acc, 0.0f);
    __syncthreads();

    if (j < C_OUT) {
        float o = b2[j];
#pragma unroll 8
        for (int hh = 0; hh < H_DIM; ++hh)
            o = fmaf(h1[hh], W2[hh * C_OUT + j], o);
        out[(size_t)b * C_OUT + j] = o;
    }
}

extern "C" void kernel_launch(void* const* d_in, const int* in_sizes, int n_in,
                              void* d_out, int out_size, void* d_ws, size_t ws_size,
                              hipStream_t stream) {
    const float* verts  = (const float*)d_in[0];   // [B,V,3]
    const float* coords = (const float*)d_in[1];   // [B,N,3]
    const float* feats  = (const float*)d_in[2];   // [B,N,H]
    const float* W1     = (const float*)d_in[3];   // [H,H]
    const float* b1     = (const float*)d_in[4];   // [H]
    const float* W2     = (const float*)d_in[5];   // [H,C_OUT]
    const float* b2     = (const float*)d_in[6];   // [C_OUT]
    float* out = (float*)d_out;                    // [B,C_OUT]

    // workspace layout
    unsigned long long* mi64 = (unsigned long long*)d_ws;                 // B*V u64 = 1 MB
    float* partial = (float*)((char*)d_ws + (size_t)B_GR * V_PTS * 8);    // B*SEGS*H = 128 KB

    hipMemsetAsync(mi64, 0xFF, (size_t)B_GR * V_PTS * 8, stream);         // graph-legal memset node
    k_argmin<<<B_GR * VBLKS * NSPLIT, 256, 0, stream>>>(verts, coords, mi64);
    k_pool  <<<B_GR * SEGS,           256, 0, stream>>>(mi64, feats, partial);
    k_mlp   <<<B_GR,                  128, 0, stream>>>(partial, W1, b1, W2, b2, out);
}